// Round 1
// baseline (318.510 us; speedup 1.0000x reference)
//
#include <hip/hip_runtime.h>

// Problem: B=4, T=4096, C=1024, H=64 single attention head, causal, NO 1/sqrt(d) scale.
// Plan: proj kernel (f32 exact) -> q,k as bf16 hi/lo pairs + V transposed bf16;
//       flash-attention kernel: QK^T with 3-term split-bf16 MFMA, f32 online softmax,
//       PV in bf16 MFMA. Output f32.

typedef __attribute__((ext_vector_type(8))) short bf16x8;
typedef __attribute__((ext_vector_type(4))) float f32x4;

__device__ __forceinline__ unsigned short f2bf(float f) {
  unsigned u = __float_as_uint(f);
  u += 0x7fffu + ((u >> 16) & 1u);   // RTNE (finite values only here)
  return (unsigned short)(u >> 16);
}
__device__ __forceinline__ float bf2f(unsigned short s) {
  return __uint_as_float(((unsigned)s) << 16);
}

// ---------------- projection: [16384 x 1024] * [1024 x 192] in f32 ----------------
// grid 512 blocks (32 rows each), 256 threads. Thread tile: 2 rows x 12 cols.
__global__ __launch_bounds__(256) void proj_kernel(
    const float* __restrict__ x, const float* __restrict__ Wq,
    const float* __restrict__ Wk, const float* __restrict__ Wv,
    unsigned short* __restrict__ qh, unsigned short* __restrict__ ql,
    unsigned short* __restrict__ kh, unsigned short* __restrict__ kl,
    unsigned short* __restrict__ vt) {
  __shared__ float xs[32][34];    // xs[kk][r], transposed x tile (32 rows x 32 k)
  __shared__ float ws[32][192];   // ws[kk][n], n = concat(q,k,v) columns
  const int tid = threadIdx.x;
  const int tc = tid & 15;        // col group: cols tc*12 .. tc*12+11
  const int tr = tid >> 4;        // row group: rows tr*2 .. tr*2+1
  const int row0 = blockIdx.x * 32;

  float acc[2][12];
#pragma unroll
  for (int i = 0; i < 2; ++i)
#pragma unroll
    for (int j = 0; j < 12; ++j) acc[i][j] = 0.f;

  for (int k0 = 0; k0 < 1024; k0 += 32) {
    __syncthreads();
    {
      // x tile: 32 rows x 32 k = 256 float4, one per thread (transpose into LDS)
      int r = tid >> 3;
      int kk = (tid & 7) * 4;
      const float4 v = *reinterpret_cast<const float4*>(
          &x[(size_t)(row0 + r) * 1024 + k0 + kk]);
      xs[kk + 0][r] = v.x; xs[kk + 1][r] = v.y;
      xs[kk + 2][r] = v.z; xs[kk + 3][r] = v.w;
      // W tile: 32 k x 192 n = 1536 float4-groups/4 -> 6 float4 per thread
#pragma unroll
      for (int i = 0; i < 6; ++i) {
        int f = tid * 6 + i;
        int kk2 = f / 48;
        int n4 = (f % 48) * 4;
        const float* wp = (n4 < 64) ? Wq : ((n4 < 128) ? Wk : Wv);
        int h = n4 & 63;
        const float4 wv = *reinterpret_cast<const float4*>(
            &wp[(size_t)(k0 + kk2) * 64 + h]);
        *reinterpret_cast<float4*>(&ws[kk2][n4]) = wv;
      }
    }
    __syncthreads();
#pragma unroll
    for (int kk = 0; kk < 32; ++kk) {
      float a[2], wv[12];
      *reinterpret_cast<float2*>(a) =
          *reinterpret_cast<const float2*>(&xs[kk][tr * 2]);
      *reinterpret_cast<float4*>(&wv[0]) =
          *reinterpret_cast<const float4*>(&ws[kk][tc * 12]);
      *reinterpret_cast<float4*>(&wv[4]) =
          *reinterpret_cast<const float4*>(&ws[kk][tc * 12 + 4]);
      *reinterpret_cast<float4*>(&wv[8]) =
          *reinterpret_cast<const float4*>(&ws[kk][tc * 12 + 8]);
#pragma unroll
      for (int i = 0; i < 2; ++i)
#pragma unroll
        for (int j = 0; j < 12; ++j)
          acc[i][j] = fmaf(a[i], wv[j], acc[i][j]);
    }
  }
  // epilogue: split q,k into bf16 hi/lo; v transposed [B][64][T]
#pragma unroll
  for (int i = 0; i < 2; ++i) {
    int row = row0 + tr * 2 + i;          // global row in [0,16384)
    int b = row >> 12, t = row & 4095;
#pragma unroll
    for (int j = 0; j < 12; ++j) {
      int n = tc * 12 + j;
      float val = acc[i][j];
      int h = n & 63;
      size_t qkaddr = (size_t)row * 64 + h;
      if (n < 64) {
        unsigned short hi = f2bf(val);
        qh[qkaddr] = hi;
        ql[qkaddr] = f2bf(val - bf2f(hi));
      } else if (n < 128) {
        unsigned short hi = f2bf(val);
        kh[qkaddr] = hi;
        kl[qkaddr] = f2bf(val - bf2f(hi));
      } else {
        vt[((size_t)b * 64 + h) * 4096 + t] = f2bf(val);
      }
    }
  }
}

// ---------------- flash attention ----------------
// grid (64, 4), 256 threads = 4 waves. Wave w handles 16 q-rows:
// tile16 = {bx, 127-bx, 128+bx, 255-bx}[w]  (balances causal work per block).
// MFMA 16x16x32 bf16. C/D layout: col=lane&15, row=(lane>>4)*4+reg (m89-verified).
// A layout: row=lane&15, k=(lane>>4)*8+j ; B layout: col=lane&15, k=(lane>>4)*8+j.
__global__ __launch_bounds__(256) void attn_kernel(
    const unsigned short* __restrict__ qh, const unsigned short* __restrict__ ql,
    const unsigned short* __restrict__ kh, const unsigned short* __restrict__ kl,
    const unsigned short* __restrict__ vt, float* __restrict__ out) {
  __shared__ __align__(16) unsigned short pbuf[4][16][88];  // per-wave P tile, padded
  const int tid = threadIdx.x;
  const int w = tid >> 6;
  const int lane = tid & 63;
  const int l16 = lane & 15;
  const int g = lane >> 4;
  const int bx = blockIdx.x;
  const int b = blockIdx.y;
  const int tile16 = (w & 1) ? (((w & 2) ? 255 : 127) - bx)
                             : (((w & 2) ? 128 : 0) + bx);
  const int q0 = tile16 * 16;                 // q-row offset within batch
  const size_t rowbase = (size_t)b * 4096;

  // Q fragments (A-operand), hi and lo
  bf16x8 qhf[2], qlf[2];
#pragma unroll
  for (int s = 0; s < 2; ++s) {
    size_t a = (rowbase + q0 + l16) * 64 + s * 32 + g * 8;
    qhf[s] = *reinterpret_cast<const bf16x8*>(&qh[a]);
    qlf[s] = *reinterpret_cast<const bf16x8*>(&ql[a]);
  }

  f32x4 o[4];
  float m_r[4], l_r[4];
#pragma unroll
  for (int hb = 0; hb < 4; ++hb) {
    f32x4 z = {0.f, 0.f, 0.f, 0.f};
    o[hb] = z;
  }
#pragma unroll
  for (int j = 0; j < 4; ++j) { m_r[j] = -1e30f; l_r[j] = 0.f; }

  const int nkv = (q0 + 15) / 64 + 1;   // causal: kv tiles 0 .. nkv-1 (64 wide)
  for (int t = 0; t < nkv; ++t) {
    const int kv0 = t * 64;
    f32x4 s_acc[4];
    // S = Q K^T with 3-term split: qh*kh + qh*kl + ql*kh  (f32 accumulate)
#pragma unroll
    for (int kb = 0; kb < 4; ++kb) {
      bf16x8 khf[2], klf[2];
#pragma unroll
      for (int s = 0; s < 2; ++s) {
        size_t a = (rowbase + kv0 + kb * 16 + l16) * 64 + s * 32 + g * 8;
        khf[s] = *reinterpret_cast<const bf16x8*>(&kh[a]);
        klf[s] = *reinterpret_cast<const bf16x8*>(&kl[a]);
      }
      f32x4 acc = {0.f, 0.f, 0.f, 0.f};
#pragma unroll
      for (int s = 0; s < 2; ++s) {
        acc = __builtin_amdgcn_mfma_f32_16x16x32_bf16(qhf[s], khf[s], acc, 0, 0, 0);
        acc = __builtin_amdgcn_mfma_f32_16x16x32_bf16(qhf[s], klf[s], acc, 0, 0, 0);
        acc = __builtin_amdgcn_mfma_f32_16x16x32_bf16(qlf[s], khf[s], acc, 0, 0, 0);
      }
      s_acc[kb] = acc;
    }
    // causal mask (only the last kv tile can straddle the diagonal)
    if (t == nkv - 1) {
#pragma unroll
      for (int kb = 0; kb < 4; ++kb)
#pragma unroll
        for (int j = 0; j < 4; ++j) {
          int kvg = kv0 + kb * 16 + l16;
          int qg = q0 + 4 * g + j;
          if (kvg > qg) s_acc[kb][j] = -1e30f;
        }
    }
    // online softmax (row r = 4*g+j lives in the 16 lanes sharing g)
#pragma unroll
    for (int j = 0; j < 4; ++j) {
      float rm = fmaxf(fmaxf(s_acc[0][j], s_acc[1][j]),
                       fmaxf(s_acc[2][j], s_acc[3][j]));
      rm = fmaxf(rm, __shfl_xor(rm, 1));
      rm = fmaxf(rm, __shfl_xor(rm, 2));
      rm = fmaxf(rm, __shfl_xor(rm, 4));
      rm = fmaxf(rm, __shfl_xor(rm, 8));
      float mn = fmaxf(m_r[j], rm);
      float al = __expf(m_r[j] - mn);
      float ps = 0.f;
#pragma unroll
      for (int kb = 0; kb < 4; ++kb) {
        float p = __expf(s_acc[kb][j] - mn);
        s_acc[kb][j] = p;
        ps += p;
      }
      ps += __shfl_xor(ps, 1);
      ps += __shfl_xor(ps, 2);
      ps += __shfl_xor(ps, 4);
      ps += __shfl_xor(ps, 8);
      l_r[j] = l_r[j] * al + ps;
      m_r[j] = mn;
#pragma unroll
      for (int hb = 0; hb < 4; ++hb) o[hb][j] *= al;
    }
    // P (D-layout) -> LDS -> reload in A-layout. Per-wave buffer, wave-internal only.
#pragma unroll
    for (int kb = 0; kb < 4; ++kb)
#pragma unroll
      for (int j = 0; j < 4; ++j)
        pbuf[w][4 * g + j][kb * 16 + l16] = f2bf(s_acc[kb][j]);
    asm volatile("s_waitcnt lgkmcnt(0)" ::: "memory");
    // PV: O += P * V   (V read from transposed layout [B][64][T], contiguous 16B)
#pragma unroll
    for (int ks = 0; ks < 2; ++ks) {
      bf16x8 pa = *reinterpret_cast<const bf16x8*>(&pbuf[w][l16][ks * 32 + g * 8]);
#pragma unroll
      for (int hb = 0; hb < 4; ++hb) {
        size_t a = ((size_t)b * 64 + hb * 16 + l16) * 4096 + kv0 + ks * 32 + g * 8;
        bf16x8 vf = *reinterpret_cast<const bf16x8*>(&vt[a]);
        o[hb] = __builtin_amdgcn_mfma_f32_16x16x32_bf16(pa, vf, o[hb], 0, 0, 0);
      }
    }
  }
  // epilogue: divide by softmax denom, store f32
#pragma unroll
  for (int hb = 0; hb < 4; ++hb)
#pragma unroll
    for (int j = 0; j < 4; ++j) {
      size_t a = (rowbase + q0 + 4 * g + j) * 64 + hb * 16 + l16;
      out[a] = o[hb][j] / l_r[j];
    }
}

extern "C" void kernel_launch(void* const* d_in, const int* in_sizes, int n_in,
                              void* d_out, int out_size, void* d_ws, size_t ws_size,
                              hipStream_t stream) {
  const float* x  = (const float*)d_in[0];
  const float* Wq = (const float*)d_in[1];
  const float* Wk = (const float*)d_in[2];
  const float* Wv = (const float*)d_in[3];
  float* out = (float*)d_out;

  const size_t N = (size_t)4 * 4096 * 64;   // 1,048,576 elements per q/k/v array
  unsigned short* qh = (unsigned short*)d_ws;
  unsigned short* ql = qh + N;
  unsigned short* kh = ql + N;
  unsigned short* kl = kh + N;
  unsigned short* vt = kl + N;              // [B][64][T] transposed V

  proj_kernel<<<dim3(512), dim3(256), 0, stream>>>(x, Wq, Wk, Wv, qh, ql, kh, kl, vt);
  attn_kernel<<<dim3(64, 4), dim3(256), 0, stream>>>(qh, ql, kh, kl, vt, out);
}

// Round 2
// 266.136 us; speedup vs baseline: 1.1968x; 1.1968x over previous
//
#include <hip/hip_runtime.h>

// Problem: B=4, T=4096, C=1024, H=64 single attention head, causal, NO 1/sqrt(d) scale.
// proj kernel (f32 exact) -> q,k as bf16 hi/lo pairs + V transposed bf16;
// flash-decode attention: KV-split partials (one wave per partial) + combine kernel.
// QK^T uses 3-term split-bf16 MFMA, f32 online softmax, PV in bf16 MFMA. Output f32.

typedef __attribute__((ext_vector_type(8))) short bf16x8;
typedef __attribute__((ext_vector_type(4))) float f32x4;

__device__ __forceinline__ unsigned short f2bf(float f) {
  unsigned u = __float_as_uint(f);
  u += 0x7fffu + ((u >> 16) & 1u);   // RTNE (finite values only here)
  return (unsigned short)(u >> 16);
}
__device__ __forceinline__ float bf2f(unsigned short s) {
  return __uint_as_float(((unsigned)s) << 16);
}
__device__ __forceinline__ unsigned cvt_pk_bf16(float lo, float hi) {
  unsigned r;
  asm("v_cvt_pk_bf16_f32 %0, %1, %2" : "=v"(r) : "v"(lo), "v"(hi));
  return r;
}

// ---------------- projection: [16384 x 1024] * [1024 x 192] in f32 ----------------
__global__ __launch_bounds__(256) void proj_kernel(
    const float* __restrict__ x, const float* __restrict__ Wq,
    const float* __restrict__ Wk, const float* __restrict__ Wv,
    unsigned short* __restrict__ qh, unsigned short* __restrict__ ql,
    unsigned short* __restrict__ kh, unsigned short* __restrict__ kl,
    unsigned short* __restrict__ vt) {
  __shared__ float xs[32][34];    // xs[kk][r], transposed x tile (32 rows x 32 k)
  __shared__ float ws[32][192];   // ws[kk][n], n = concat(q,k,v) columns
  const int tid = threadIdx.x;
  const int tc = tid & 15;        // col group: cols tc*12 .. tc*12+11
  const int tr = tid >> 4;        // row group: rows tr*2 .. tr*2+1
  const int row0 = blockIdx.x * 32;

  float acc[2][12];
#pragma unroll
  for (int i = 0; i < 2; ++i)
#pragma unroll
    for (int j = 0; j < 12; ++j) acc[i][j] = 0.f;

  for (int k0 = 0; k0 < 1024; k0 += 32) {
    __syncthreads();
    {
      int r = tid >> 3;
      int kk = (tid & 7) * 4;
      const float4 v = *reinterpret_cast<const float4*>(
          &x[(size_t)(row0 + r) * 1024 + k0 + kk]);
      xs[kk + 0][r] = v.x; xs[kk + 1][r] = v.y;
      xs[kk + 2][r] = v.z; xs[kk + 3][r] = v.w;
#pragma unroll
      for (int i = 0; i < 6; ++i) {
        int f = tid * 6 + i;
        int kk2 = f / 48;
        int n4 = (f % 48) * 4;
        const float* wp = (n4 < 64) ? Wq : ((n4 < 128) ? Wk : Wv);
        int h = n4 & 63;
        const float4 wv = *reinterpret_cast<const float4*>(
            &wp[(size_t)(k0 + kk2) * 64 + h]);
        *reinterpret_cast<float4*>(&ws[kk2][n4]) = wv;
      }
    }
    __syncthreads();
#pragma unroll
    for (int kk = 0; kk < 32; ++kk) {
      float a[2], wv[12];
      *reinterpret_cast<float2*>(a) =
          *reinterpret_cast<const float2*>(&xs[kk][tr * 2]);
      *reinterpret_cast<float4*>(&wv[0]) =
          *reinterpret_cast<const float4*>(&ws[kk][tc * 12]);
      *reinterpret_cast<float4*>(&wv[4]) =
          *reinterpret_cast<const float4*>(&ws[kk][tc * 12 + 4]);
      *reinterpret_cast<float4*>(&wv[8]) =
          *reinterpret_cast<const float4*>(&ws[kk][tc * 12 + 8]);
#pragma unroll
      for (int i = 0; i < 2; ++i)
#pragma unroll
        for (int j = 0; j < 12; ++j)
          acc[i][j] = fmaf(a[i], wv[j], acc[i][j]);
    }
  }
#pragma unroll
  for (int i = 0; i < 2; ++i) {
    int row = row0 + tr * 2 + i;
    int b = row >> 12, t = row & 4095;
#pragma unroll
    for (int j = 0; j < 12; ++j) {
      int n = tc * 12 + j;
      float val = acc[i][j];
      int h = n & 63;
      size_t qkaddr = (size_t)row * 64 + h;
      if (n < 64) {
        unsigned short hi = f2bf(val);
        qh[qkaddr] = hi;
        ql[qkaddr] = f2bf(val - bf2f(hi));
      } else if (n < 128) {
        unsigned short hi = f2bf(val);
        kh[qkaddr] = hi;
        kl[qkaddr] = f2bf(val - bf2f(hi));
      } else {
        vt[((size_t)b * 64 + h) * 4096 + t] = f2bf(val);
      }
    }
  }
}

// ---------------- flash-decode attention: partial kernel ----------------
// grid (256 qtiles, 8 kv-parts, 4 batch), 64 threads (1 wave).
// Tile i: ntiles = (i>>2)+1 kv-tiles (64 wide), nparts = (i>>5)+1.
// Part p covers kv tiles [8p, min(ntiles, 8p+8)). Writes normalized partial
// (o/l) [16][64] f32 + (m,l) [16] each to compact slots (prefix-sum indexed).
__global__ __launch_bounds__(64) void attn_part_kernel(
    const unsigned short* __restrict__ qh, const unsigned short* __restrict__ ql,
    const unsigned short* __restrict__ kh, const unsigned short* __restrict__ kl,
    const unsigned short* __restrict__ vt,
    float* __restrict__ OP, float* __restrict__ ML) {
  __shared__ __align__(16) unsigned short pbuf[16][88];
  const int lane = threadIdx.x;
  const int l16 = lane & 15;
  const int g = lane >> 4;
  const int i = blockIdx.x;
  const int p = blockIdx.y;
  const int b = blockIdx.z;
  const int nparts = (i >> 5) + 1;
  if (p >= nparts) return;
  const int ntiles = (i >> 2) + 1;
  const int t0 = p * 8;
  const int t1 = min(ntiles, t0 + 8);
  const int q0 = i * 16;
  const size_t rowbase = (size_t)b * 4096;

  // Q fragments (A-operand), hi and lo
  bf16x8 qhf[2], qlf[2];
#pragma unroll
  for (int s = 0; s < 2; ++s) {
    size_t a = (rowbase + q0 + l16) * 64 + s * 32 + g * 8;
    qhf[s] = *reinterpret_cast<const bf16x8*>(&qh[a]);
    qlf[s] = *reinterpret_cast<const bf16x8*>(&ql[a]);
  }

  f32x4 o[4];
  float m_r[4], l_r[4];
#pragma unroll
  for (int hb = 0; hb < 4; ++hb) {
    f32x4 z = {0.f, 0.f, 0.f, 0.f};
    o[hb] = z;
  }
#pragma unroll
  for (int j = 0; j < 4; ++j) { m_r[j] = -1e30f; l_r[j] = 0.f; }

  for (int t = t0; t < t1; ++t) {
    const int kv0 = t * 64;
    // V loads hoisted early (independent of QK result)
    bf16x8 vf[2][4];
#pragma unroll
    for (int ks = 0; ks < 2; ++ks)
#pragma unroll
      for (int hb = 0; hb < 4; ++hb) {
        size_t a = ((size_t)b * 64 + hb * 16 + l16) * 4096 + kv0 + ks * 32 + g * 8;
        vf[ks][hb] = *reinterpret_cast<const bf16x8*>(&vt[a]);
      }
    // S = Q K^T with 3-term split: qh*kh + qh*kl + ql*kh  (f32 accumulate)
    f32x4 s_acc[4];
#pragma unroll
    for (int kb = 0; kb < 4; ++kb) {
      bf16x8 khf[2], klf[2];
#pragma unroll
      for (int s = 0; s < 2; ++s) {
        size_t a = (rowbase + kv0 + kb * 16 + l16) * 64 + s * 32 + g * 8;
        khf[s] = *reinterpret_cast<const bf16x8*>(&kh[a]);
        klf[s] = *reinterpret_cast<const bf16x8*>(&kl[a]);
      }
      f32x4 acc = {0.f, 0.f, 0.f, 0.f};
#pragma unroll
      for (int s = 0; s < 2; ++s) {
        acc = __builtin_amdgcn_mfma_f32_16x16x32_bf16(qhf[s], khf[s], acc, 0, 0, 0);
        acc = __builtin_amdgcn_mfma_f32_16x16x32_bf16(qhf[s], klf[s], acc, 0, 0, 0);
        acc = __builtin_amdgcn_mfma_f32_16x16x32_bf16(qlf[s], khf[s], acc, 0, 0, 0);
      }
      s_acc[kb] = acc;
    }
    // causal mask (only the globally-last kv tile straddles the diagonal)
    if (t == ntiles - 1) {
#pragma unroll
      for (int kb = 0; kb < 4; ++kb)
#pragma unroll
        for (int j = 0; j < 4; ++j) {
          int kvg = kv0 + kb * 16 + l16;
          int qg = q0 + 4 * g + j;
          if (kvg > qg) s_acc[kb][j] = -1e30f;
        }
    }
    // online softmax (row r = 4*g+j; 64 kv cols spread over 16 lanes x 4 kb)
#pragma unroll
    for (int j = 0; j < 4; ++j) {
      float rm = fmaxf(fmaxf(s_acc[0][j], s_acc[1][j]),
                       fmaxf(s_acc[2][j], s_acc[3][j]));
      rm = fmaxf(rm, __shfl_xor(rm, 1));
      rm = fmaxf(rm, __shfl_xor(rm, 2));
      rm = fmaxf(rm, __shfl_xor(rm, 4));
      rm = fmaxf(rm, __shfl_xor(rm, 8));
      float mn = fmaxf(m_r[j], rm);
      float al = __expf(m_r[j] - mn);
      float ps = 0.f;
#pragma unroll
      for (int kb = 0; kb < 4; ++kb) {
        float pv = __expf(s_acc[kb][j] - mn);
        s_acc[kb][j] = pv;
        ps += pv;
      }
      ps += __shfl_xor(ps, 1);
      ps += __shfl_xor(ps, 2);
      ps += __shfl_xor(ps, 4);
      ps += __shfl_xor(ps, 8);
      l_r[j] = l_r[j] * al + ps;
      m_r[j] = mn;
#pragma unroll
      for (int hb = 0; hb < 4; ++hb) o[hb][j] *= al;
    }
    // P (D-layout) -> LDS -> reload in A-layout (wave-internal, packed convert)
#pragma unroll
    for (int kb = 0; kb < 4; ++kb) {
      unsigned pk0 = cvt_pk_bf16(s_acc[kb][0], s_acc[kb][1]);
      unsigned pk1 = cvt_pk_bf16(s_acc[kb][2], s_acc[kb][3]);
      pbuf[4 * g + 0][kb * 16 + l16] = (unsigned short)pk0;
      pbuf[4 * g + 1][kb * 16 + l16] = (unsigned short)(pk0 >> 16);
      pbuf[4 * g + 2][kb * 16 + l16] = (unsigned short)pk1;
      pbuf[4 * g + 3][kb * 16 + l16] = (unsigned short)(pk1 >> 16);
    }
    asm volatile("s_waitcnt lgkmcnt(0)" ::: "memory");
    // PV: O += P * V
#pragma unroll
    for (int ks = 0; ks < 2; ++ks) {
      bf16x8 pa = *reinterpret_cast<const bf16x8*>(&pbuf[l16][ks * 32 + g * 8]);
#pragma unroll
      for (int hb = 0; hb < 4; ++hb)
        o[hb] = __builtin_amdgcn_mfma_f32_16x16x32_bf16(pa, vf[ks][hb], o[hb], 0, 0, 0);
    }
  }
  // epilogue: compact slot = b*1152 + base_i + p; write normalized o, (m,l)
  const int f = i >> 5, r = i & 31;
  const size_t slot = (size_t)b * 1152 + (size_t)(i + 16 * f * (f - 1) + r * f) + p;
  float* op = OP + slot * 1024;
#pragma unroll
  for (int hb = 0; hb < 4; ++hb)
#pragma unroll
    for (int j = 0; j < 4; ++j)
      op[(4 * g + j) * 64 + hb * 16 + l16] = o[hb][j] / l_r[j];
  if (l16 == 0) {
#pragma unroll
    for (int j = 0; j < 4; ++j) {
      ML[slot * 32 + 4 * g + j] = m_r[j];
      ML[slot * 32 + 16 + 4 * g + j] = l_r[j];
    }
  }
}

// ---------------- combine partials ----------------
// grid (256 qtiles, 4 batch), 64 threads. Lane = head col h.
__global__ __launch_bounds__(64) void attn_combine_kernel(
    const float* __restrict__ OP, const float* __restrict__ ML,
    float* __restrict__ out) {
  const int lane = threadIdx.x;
  const int i = blockIdx.x;
  const int b = blockIdx.y;
  const int nparts = (i >> 5) + 1;
  const int f = i >> 5, r = i & 31;
  const size_t base = (size_t)b * 1152 + (size_t)(i + 16 * f * (f - 1) + r * f);
  const int q0 = i * 16;

  for (int row = 0; row < 16; ++row) {
    float M = -1e30f;
    float mv[8], lv[8];
#pragma unroll 8
    for (int p = 0; p < 8; ++p) {
      if (p < nparts) {
        mv[p] = ML[(base + p) * 32 + row];
        lv[p] = ML[(base + p) * 32 + 16 + row];
        M = fmaxf(M, mv[p]);
      } else {
        mv[p] = -1e30f;
        lv[p] = 0.f;
      }
    }
    float wsum = 0.f, acc = 0.f;
#pragma unroll 8
    for (int p = 0; p < 8; ++p) {
      if (p < nparts) {
        float w = lv[p] * __expf(mv[p] - M);
        wsum += w;
        acc += w * OP[(base + p) * 1024 + row * 64 + lane];
      }
    }
    out[((size_t)b * 4096 + q0 + row) * 64 + lane] = acc / wsum;
  }
}

// ---------------- fallback single-pass attention (round-1, used if ws too small) ----
__global__ __launch_bounds__(256) void attn_kernel(
    const unsigned short* __restrict__ qh, const unsigned short* __restrict__ ql,
    const unsigned short* __restrict__ kh, const unsigned short* __restrict__ kl,
    const unsigned short* __restrict__ vt, float* __restrict__ out) {
  __shared__ __align__(16) unsigned short pbuf[4][16][88];
  const int tid = threadIdx.x;
  const int w = tid >> 6;
  const int lane = tid & 63;
  const int l16 = lane & 15;
  const int g = lane >> 4;
  const int bx = blockIdx.x;
  const int b = blockIdx.y;
  const int tile16 = (w & 1) ? (((w & 2) ? 255 : 127) - bx)
                             : (((w & 2) ? 128 : 0) + bx);
  const int q0 = tile16 * 16;
  const size_t rowbase = (size_t)b * 4096;

  bf16x8 qhf[2], qlf[2];
#pragma unroll
  for (int s = 0; s < 2; ++s) {
    size_t a = (rowbase + q0 + l16) * 64 + s * 32 + g * 8;
    qhf[s] = *reinterpret_cast<const bf16x8*>(&qh[a]);
    qlf[s] = *reinterpret_cast<const bf16x8*>(&ql[a]);
  }
  f32x4 o[4];
  float m_r[4], l_r[4];
#pragma unroll
  for (int hb = 0; hb < 4; ++hb) {
    f32x4 z = {0.f, 0.f, 0.f, 0.f};
    o[hb] = z;
  }
#pragma unroll
  for (int j = 0; j < 4; ++j) { m_r[j] = -1e30f; l_r[j] = 0.f; }

  const int nkv = (q0 + 15) / 64 + 1;
  for (int t = 0; t < nkv; ++t) {
    const int kv0 = t * 64;
    f32x4 s_acc[4];
#pragma unroll
    for (int kb = 0; kb < 4; ++kb) {
      bf16x8 khf[2], klf[2];
#pragma unroll
      for (int s = 0; s < 2; ++s) {
        size_t a = (rowbase + kv0 + kb * 16 + l16) * 64 + s * 32 + g * 8;
        khf[s] = *reinterpret_cast<const bf16x8*>(&kh[a]);
        klf[s] = *reinterpret_cast<const bf16x8*>(&kl[a]);
      }
      f32x4 acc = {0.f, 0.f, 0.f, 0.f};
#pragma unroll
      for (int s = 0; s < 2; ++s) {
        acc = __builtin_amdgcn_mfma_f32_16x16x32_bf16(qhf[s], khf[s], acc, 0, 0, 0);
        acc = __builtin_amdgcn_mfma_f32_16x16x32_bf16(qhf[s], klf[s], acc, 0, 0, 0);
        acc = __builtin_amdgcn_mfma_f32_16x16x32_bf16(qlf[s], khf[s], acc, 0, 0, 0);
      }
      s_acc[kb] = acc;
    }
    if (t == nkv - 1) {
#pragma unroll
      for (int kb = 0; kb < 4; ++kb)
#pragma unroll
        for (int j = 0; j < 4; ++j) {
          int kvg = kv0 + kb * 16 + l16;
          int qg = q0 + 4 * g + j;
          if (kvg > qg) s_acc[kb][j] = -1e30f;
        }
    }
#pragma unroll
    for (int j = 0; j < 4; ++j) {
      float rm = fmaxf(fmaxf(s_acc[0][j], s_acc[1][j]),
                       fmaxf(s_acc[2][j], s_acc[3][j]));
      rm = fmaxf(rm, __shfl_xor(rm, 1));
      rm = fmaxf(rm, __shfl_xor(rm, 2));
      rm = fmaxf(rm, __shfl_xor(rm, 4));
      rm = fmaxf(rm, __shfl_xor(rm, 8));
      float mn = fmaxf(m_r[j], rm);
      float al = __expf(m_r[j] - mn);
      float ps = 0.f;
#pragma unroll
      for (int kb = 0; kb < 4; ++kb) {
        float pv = __expf(s_acc[kb][j] - mn);
        s_acc[kb][j] = pv;
        ps += pv;
      }
      ps += __shfl_xor(ps, 1);
      ps += __shfl_xor(ps, 2);
      ps += __shfl_xor(ps, 4);
      ps += __shfl_xor(ps, 8);
      l_r[j] = l_r[j] * al + ps;
      m_r[j] = mn;
#pragma unroll
      for (int hb = 0; hb < 4; ++hb) o[hb][j] *= al;
    }
#pragma unroll
    for (int kb = 0; kb < 4; ++kb)
#pragma unroll
      for (int j = 0; j < 4; ++j)
        pbuf[w][4 * g + j][kb * 16 + l16] = f2bf(s_acc[kb][j]);
    asm volatile("s_waitcnt lgkmcnt(0)" ::: "memory");
#pragma unroll
    for (int ks = 0; ks < 2; ++ks) {
      bf16x8 pa = *reinterpret_cast<const bf16x8*>(&pbuf[w][l16][ks * 32 + g * 8]);
#pragma unroll
      for (int hb = 0; hb < 4; ++hb) {
        size_t a = ((size_t)b * 64 + hb * 16 + l16) * 4096 + kv0 + ks * 32 + g * 8;
        bf16x8 vfr = *reinterpret_cast<const bf16x8*>(&vt[a]);
        o[hb] = __builtin_amdgcn_mfma_f32_16x16x32_bf16(pa, vfr, o[hb], 0, 0, 0);
      }
    }
  }
#pragma unroll
  for (int hb = 0; hb < 4; ++hb)
#pragma unroll
    for (int j = 0; j < 4; ++j) {
      size_t a = (rowbase + q0 + 4 * g + j) * 64 + hb * 16 + l16;
      out[a] = o[hb][j] / l_r[j];
    }
}

extern "C" void kernel_launch(void* const* d_in, const int* in_sizes, int n_in,
                              void* d_out, int out_size, void* d_ws, size_t ws_size,
                              hipStream_t stream) {
  const float* x  = (const float*)d_in[0];
  const float* Wq = (const float*)d_in[1];
  const float* Wk = (const float*)d_in[2];
  const float* Wv = (const float*)d_in[3];
  float* out = (float*)d_out;

  const size_t N = (size_t)4 * 4096 * 64;   // elements per q/k/v array
  unsigned short* qh = (unsigned short*)d_ws;
  unsigned short* ql = qh + N;
  unsigned short* kh = ql + N;
  unsigned short* kl = kh + N;
  unsigned short* vt = kl + N;              // [B][64][T] transposed V
  float* OP = (float*)(vt + N);             // 4608 slots x 16 x 64 f32
  float* ML = OP + (size_t)4608 * 1024;     // 4608 slots x 32 f32

  const size_t need = 5 * N * 2 + (size_t)4608 * 1024 * 4 + (size_t)4608 * 32 * 4;

  proj_kernel<<<dim3(512), dim3(256), 0, stream>>>(x, Wq, Wk, Wv, qh, ql, kh, kl, vt);
  if (ws_size >= need) {
    attn_part_kernel<<<dim3(256, 8, 4), dim3(64), 0, stream>>>(qh, ql, kh, kl, vt, OP, ML);
    attn_combine_kernel<<<dim3(256, 4), dim3(64), 0, stream>>>(OP, ML, out);
  } else {
    attn_kernel<<<dim3(64, 4), dim3(256), 0, stream>>>(qh, ql, kh, kl, vt, out);
  }
}

// Round 3
// 199.722 us; speedup vs baseline: 1.5948x; 1.3325x over previous
//
#include <hip/hip_runtime.h>
#include <hip/hip_fp16.h>

// B=4, T=4096, C=1024, H=64 single attention head, causal, NO 1/sqrt(d) scale.
// wsplit: W -> hi/lo bf16 fragment-stream. proj_mfma: 3-term split-bf16 MFMA GEMM
// producing qh/ql/kh/kl (hi/lo bf16) + vt (bf16, [B][64][T]). flash-decode attn
// (KV-split partials, f16 partial store) + combine. Output f32.

typedef __attribute__((ext_vector_type(8))) short bf16x8;
typedef __attribute__((ext_vector_type(8))) unsigned short u16x8;
typedef __attribute__((ext_vector_type(4))) float f32x4;

__device__ __forceinline__ unsigned short f2bf(float f) {
  unsigned u = __float_as_uint(f);
  u += 0x7fffu + ((u >> 16) & 1u);   // RTNE (finite values only here)
  return (unsigned short)(u >> 16);
}
__device__ __forceinline__ float bf2f(unsigned short s) {
  return __uint_as_float(((unsigned)s) << 16);
}
__device__ __forceinline__ unsigned cvt_pk_bf16(float lo, float hi) {
  unsigned r;
  asm("v_cvt_pk_bf16_f32 %0, %1, %2" : "=v"(r) : "v"(lo), "v"(hi));
  return r;
}

// ---------------- W split: frag-stream layout ----------------
// element (ksq, nf, g, l16, j): k = ksq*32 + g*8 + j, n = nf*16 + l16
// flat = ((ksq*12 + nf)*64 + (g*16+l16))*8 + j    (ksq in [0,32), nf in [0,12))
__global__ __launch_bounds__(256) void wsplit_kernel(
    const float* __restrict__ Wq, const float* __restrict__ Wk,
    const float* __restrict__ Wv,
    unsigned short* __restrict__ Wth, unsigned short* __restrict__ Wtl) {
  const int fl = blockIdx.x * 256 + threadIdx.x;   // [0, 24576)
  const int lane = fl & 63;
  const int rest = fl >> 6;        // [0, 384)
  const int nf = rest % 12;
  const int ksq = rest / 12;       // [0, 32)
  const int n = nf * 16 + (lane & 15);
  const int k0 = ksq * 32 + (lane >> 4) * 8;
  const float* wp = (n < 64) ? Wq : ((n < 128) ? Wk : Wv);
  const int h = n & 63;
  u16x8 hi, lo;
#pragma unroll
  for (int j = 0; j < 8; ++j) {
    float v = wp[(size_t)(k0 + j) * 64 + h];
    unsigned short hh = f2bf(v);
    hi[j] = hh;
    lo[j] = f2bf(v - bf2f(hh));
  }
  const size_t base = (size_t)fl * 8;
  *reinterpret_cast<u16x8*>(&Wth[base]) = hi;
  *reinterpret_cast<u16x8*>(&Wtl[base]) = lo;
}

// ---------------- projection via MFMA: [16384 x 1024] * [1024 x 192] ----------------
// grid 512 blocks x 256 threads (4 waves). Block: 32 rows, all 192 cols, K-step 64.
// Wave w owns cols [w*48, w*48+48) = 3 nfrags; 2 mfrags of 16 rows.
// A (x) staged in LDS as hi/lo bf16, double-buffered, padded [32][72].
// 3-term: xh*wh + xh*wl + xl*wh, f32 accum.
__global__ __launch_bounds__(256) void proj_mfma_kernel(
    const float* __restrict__ x,
    const unsigned short* __restrict__ Wth, const unsigned short* __restrict__ Wtl,
    unsigned short* __restrict__ qh, unsigned short* __restrict__ ql,
    unsigned short* __restrict__ kh, unsigned short* __restrict__ kl,
    unsigned short* __restrict__ vt) {
  __shared__ unsigned short Ah[2][32][72];
  __shared__ unsigned short Al[2][32][72];
  const int tid = threadIdx.x;
  const int w = tid >> 6;
  const int lane = tid & 63;
  const int l16 = lane & 15;
  const int g = lane >> 4;
  const int row0 = blockIdx.x * 32;
  const int sr = tid >> 3;          // staging row 0..31
  const int sc = (tid & 7) * 8;     // staging col 0..56

  f32x4 acc[2][3];
#pragma unroll
  for (int m = 0; m < 2; ++m)
#pragma unroll
    for (int f = 0; f < 3; ++f) {
      f32x4 z = {0.f, 0.f, 0.f, 0.f};
      acc[m][f] = z;
    }

  const size_t xrow = (size_t)(row0 + sr) * 1024 + sc;
  // prologue: stage step 0 into buf 0
  {
    const float4 xa = *reinterpret_cast<const float4*>(&x[xrow]);
    const float4 xb = *reinterpret_cast<const float4*>(&x[xrow + 4]);
    float v[8] = {xa.x, xa.y, xa.z, xa.w, xb.x, xb.y, xb.z, xb.w};
    u16x8 hv, lv;
#pragma unroll
    for (int j = 0; j < 8; ++j) {
      unsigned short hh = f2bf(v[j]);
      hv[j] = hh;
      lv[j] = f2bf(v[j] - bf2f(hh));
    }
    *reinterpret_cast<u16x8*>(&Ah[0][sr][sc]) = hv;
    *reinterpret_cast<u16x8*>(&Al[0][sr][sc]) = lv;
  }

  for (int step = 0; step < 16; ++step) {
    __syncthreads();
    float4 na, nb;
    if (step < 15) {
      na = *reinterpret_cast<const float4*>(&x[xrow + (size_t)(step + 1) * 64]);
      nb = *reinterpret_cast<const float4*>(&x[xrow + (size_t)(step + 1) * 64 + 4]);
    }
    const int cur = step & 1;
#pragma unroll
    for (int ks = 0; ks < 2; ++ks) {
      bf16x8 bh[3], bl[3];
#pragma unroll
      for (int f = 0; f < 3; ++f) {
        const size_t off = ((size_t)(step * 2 + ks) * 12 + (w * 3 + f)) * 512 + lane * 8;
        bh[f] = *reinterpret_cast<const bf16x8*>(&Wth[off]);
        bl[f] = *reinterpret_cast<const bf16x8*>(&Wtl[off]);
      }
      bf16x8 ah[2], al[2];
#pragma unroll
      for (int m = 0; m < 2; ++m) {
        const int ro = m * 16 + l16;
        const int co = ks * 32 + g * 8;
        ah[m] = *reinterpret_cast<const bf16x8*>(&Ah[cur][ro][co]);
        al[m] = *reinterpret_cast<const bf16x8*>(&Al[cur][ro][co]);
      }
#pragma unroll
      for (int m = 0; m < 2; ++m)
#pragma unroll
        for (int f = 0; f < 3; ++f) {
          acc[m][f] = __builtin_amdgcn_mfma_f32_16x16x32_bf16(ah[m], bh[f], acc[m][f], 0, 0, 0);
          acc[m][f] = __builtin_amdgcn_mfma_f32_16x16x32_bf16(ah[m], bl[f], acc[m][f], 0, 0, 0);
          acc[m][f] = __builtin_amdgcn_mfma_f32_16x16x32_bf16(al[m], bh[f], acc[m][f], 0, 0, 0);
        }
    }
    if (step < 15) {
      float v[8] = {na.x, na.y, na.z, na.w, nb.x, nb.y, nb.z, nb.w};
      u16x8 hv, lv;
#pragma unroll
      for (int j = 0; j < 8; ++j) {
        unsigned short hh = f2bf(v[j]);
        hv[j] = hh;
        lv[j] = f2bf(v[j] - bf2f(hh));
      }
      *reinterpret_cast<u16x8*>(&Ah[cur ^ 1][sr][sc]) = hv;
      *reinterpret_cast<u16x8*>(&Al[cur ^ 1][sr][sc]) = lv;
    }
  }

  // epilogue: C/D layout col=l16, row=4g+j
  const int b = row0 >> 12;
  const int tbase = row0 & 4095;
#pragma unroll
  for (int m = 0; m < 2; ++m)
#pragma unroll
    for (int f = 0; f < 3; ++f) {
      const int nn = w * 48 + f * 16;
      if (nn < 64) {
        const int h = nn + l16;
#pragma unroll
        for (int j = 0; j < 4; ++j) {
          const int row = row0 + m * 16 + 4 * g + j;
          const float val = acc[m][f][j];
          const unsigned short hi = f2bf(val);
          qh[(size_t)row * 64 + h] = hi;
          ql[(size_t)row * 64 + h] = f2bf(val - bf2f(hi));
        }
      } else if (nn < 128) {
        const int h = nn - 64 + l16;
#pragma unroll
        for (int j = 0; j < 4; ++j) {
          const int row = row0 + m * 16 + 4 * g + j;
          const float val = acc[m][f][j];
          const unsigned short hi = f2bf(val);
          kh[(size_t)row * 64 + h] = hi;
          kl[(size_t)row * 64 + h] = f2bf(val - bf2f(hi));
        }
      } else {
        const int h = nn - 128 + l16;
        ushort4 pv;
        pv.x = f2bf(acc[m][f][0]);
        pv.y = f2bf(acc[m][f][1]);
        pv.z = f2bf(acc[m][f][2]);
        pv.w = f2bf(acc[m][f][3]);
        const size_t a = ((size_t)b * 64 + h) * 4096 + tbase + m * 16 + 4 * g;
        *reinterpret_cast<ushort4*>(&vt[a]) = pv;
      }
    }
}

// ---------------- flash-decode attention: partial kernel ----------------
// grid (256 qtiles, 8 kv-parts, 4 batch), 64 threads (1 wave).
__global__ __launch_bounds__(64) void attn_part_kernel(
    const unsigned short* __restrict__ qh, const unsigned short* __restrict__ ql,
    const unsigned short* __restrict__ kh, const unsigned short* __restrict__ kl,
    const unsigned short* __restrict__ vt,
    __half* __restrict__ OP, float* __restrict__ ML) {
  __shared__ __align__(16) unsigned short pbuf[16][88];
  const int lane = threadIdx.x;
  const int l16 = lane & 15;
  const int g = lane >> 4;
  const int i = blockIdx.x;
  const int p = blockIdx.y;
  const int b = blockIdx.z;
  const int nparts = (i >> 5) + 1;
  if (p >= nparts) return;
  const int ntiles = (i >> 2) + 1;
  const int t0 = p * 8;
  const int t1 = min(ntiles, t0 + 8);
  const int q0 = i * 16;
  const size_t rowbase = (size_t)b * 4096;

  bf16x8 qhf[2], qlf[2];
#pragma unroll
  for (int s = 0; s < 2; ++s) {
    size_t a = (rowbase + q0 + l16) * 64 + s * 32 + g * 8;
    qhf[s] = *reinterpret_cast<const bf16x8*>(&qh[a]);
    qlf[s] = *reinterpret_cast<const bf16x8*>(&ql[a]);
  }

  f32x4 o[4];
  float m_r[4], l_r[4];
#pragma unroll
  for (int hb = 0; hb < 4; ++hb) {
    f32x4 z = {0.f, 0.f, 0.f, 0.f};
    o[hb] = z;
  }
#pragma unroll
  for (int j = 0; j < 4; ++j) { m_r[j] = -1e30f; l_r[j] = 0.f; }

  for (int t = t0; t < t1; ++t) {
    const int kv0 = t * 64;
    bf16x8 vf[2][4];
#pragma unroll
    for (int ks = 0; ks < 2; ++ks)
#pragma unroll
      for (int hb = 0; hb < 4; ++hb) {
        size_t a = ((size_t)b * 64 + hb * 16 + l16) * 4096 + kv0 + ks * 32 + g * 8;
        vf[ks][hb] = *reinterpret_cast<const bf16x8*>(&vt[a]);
      }
    f32x4 s_acc[4];
#pragma unroll
    for (int kb = 0; kb < 4; ++kb) {
      bf16x8 khf[2], klf[2];
#pragma unroll
      for (int s = 0; s < 2; ++s) {
        size_t a = (rowbase + kv0 + kb * 16 + l16) * 64 + s * 32 + g * 8;
        khf[s] = *reinterpret_cast<const bf16x8*>(&kh[a]);
        klf[s] = *reinterpret_cast<const bf16x8*>(&kl[a]);
      }
      f32x4 acc = {0.f, 0.f, 0.f, 0.f};
#pragma unroll
      for (int s = 0; s < 2; ++s) {
        acc = __builtin_amdgcn_mfma_f32_16x16x32_bf16(qhf[s], khf[s], acc, 0, 0, 0);
        acc = __builtin_amdgcn_mfma_f32_16x16x32_bf16(qhf[s], klf[s], acc, 0, 0, 0);
        acc = __builtin_amdgcn_mfma_f32_16x16x32_bf16(qlf[s], khf[s], acc, 0, 0, 0);
      }
      s_acc[kb] = acc;
    }
    if (t == ntiles - 1) {
#pragma unroll
      for (int kb = 0; kb < 4; ++kb)
#pragma unroll
        for (int j = 0; j < 4; ++j) {
          int kvg = kv0 + kb * 16 + l16;
          int qg = q0 + 4 * g + j;
          if (kvg > qg) s_acc[kb][j] = -1e30f;
        }
    }
#pragma unroll
    for (int j = 0; j < 4; ++j) {
      float rm = fmaxf(fmaxf(s_acc[0][j], s_acc[1][j]),
                       fmaxf(s_acc[2][j], s_acc[3][j]));
      rm = fmaxf(rm, __shfl_xor(rm, 1));
      rm = fmaxf(rm, __shfl_xor(rm, 2));
      rm = fmaxf(rm, __shfl_xor(rm, 4));
      rm = fmaxf(rm, __shfl_xor(rm, 8));
      float mn = fmaxf(m_r[j], rm);
      float al = __expf(m_r[j] - mn);
      float ps = 0.f;
#pragma unroll
      for (int kb = 0; kb < 4; ++kb) {
        float pv = __expf(s_acc[kb][j] - mn);
        s_acc[kb][j] = pv;
        ps += pv;
      }
      ps += __shfl_xor(ps, 1);
      ps += __shfl_xor(ps, 2);
      ps += __shfl_xor(ps, 4);
      ps += __shfl_xor(ps, 8);
      l_r[j] = l_r[j] * al + ps;
      m_r[j] = mn;
#pragma unroll
      for (int hb = 0; hb < 4; ++hb) o[hb][j] *= al;
    }
#pragma unroll
    for (int kb = 0; kb < 4; ++kb) {
      unsigned pk0 = cvt_pk_bf16(s_acc[kb][0], s_acc[kb][1]);
      unsigned pk1 = cvt_pk_bf16(s_acc[kb][2], s_acc[kb][3]);
      pbuf[4 * g + 0][kb * 16 + l16] = (unsigned short)pk0;
      pbuf[4 * g + 1][kb * 16 + l16] = (unsigned short)(pk0 >> 16);
      pbuf[4 * g + 2][kb * 16 + l16] = (unsigned short)pk1;
      pbuf[4 * g + 3][kb * 16 + l16] = (unsigned short)(pk1 >> 16);
    }
    asm volatile("s_waitcnt lgkmcnt(0)" ::: "memory");
#pragma unroll
    for (int ks = 0; ks < 2; ++ks) {
      bf16x8 pa = *reinterpret_cast<const bf16x8*>(&pbuf[l16][ks * 32 + g * 8]);
#pragma unroll
      for (int hb = 0; hb < 4; ++hb)
        o[hb] = __builtin_amdgcn_mfma_f32_16x16x32_bf16(pa, vf[ks][hb], o[hb], 0, 0, 0);
    }
  }
  const int f = i >> 5, r = i & 31;
  const size_t slot = (size_t)b * 1152 + (size_t)(i + 16 * f * (f - 1) + r * f) + p;
  __half* op = OP + slot * 1024;
#pragma unroll
  for (int hb = 0; hb < 4; ++hb)
#pragma unroll
    for (int j = 0; j < 4; ++j)
      op[(4 * g + j) * 64 + hb * 16 + l16] = __float2half(o[hb][j] / l_r[j]);
  if (l16 == 0) {
#pragma unroll
    for (int j = 0; j < 4; ++j) {
      ML[slot * 32 + 4 * g + j] = m_r[j];
      ML[slot * 32 + 16 + 4 * g + j] = l_r[j];
    }
  }
}

// ---------------- combine partials ----------------
__global__ __launch_bounds__(64) void attn_combine_kernel(
    const __half* __restrict__ OP, const float* __restrict__ ML,
    float* __restrict__ out) {
  const int lane = threadIdx.x;
  const int i = blockIdx.x;
  const int b = blockIdx.y;
  const int nparts = (i >> 5) + 1;
  const int f = i >> 5, r = i & 31;
  const size_t base = (size_t)b * 1152 + (size_t)(i + 16 * f * (f - 1) + r * f);
  const int q0 = i * 16;

  for (int row = 0; row < 16; ++row) {
    float M = -1e30f;
    float mv[8], lv[8];
#pragma unroll 8
    for (int p = 0; p < 8; ++p) {
      if (p < nparts) {
        mv[p] = ML[(base + p) * 32 + row];
        lv[p] = ML[(base + p) * 32 + 16 + row];
        M = fmaxf(M, mv[p]);
      } else {
        mv[p] = -1e30f;
        lv[p] = 0.f;
      }
    }
    float wsum = 0.f, acc = 0.f;
#pragma unroll 8
    for (int p = 0; p < 8; ++p) {
      if (p < nparts) {
        float wgt = lv[p] * __expf(mv[p] - M);
        wsum += wgt;
        acc += wgt * __half2float(OP[(base + p) * 1024 + row * 64 + lane]);
      }
    }
    out[((size_t)b * 4096 + q0 + row) * 64 + lane] = acc / wsum;
  }
}

// ---------------- fallback single-pass attention (only if ws too small) ----------
__global__ __launch_bounds__(256) void attn_kernel(
    const unsigned short* __restrict__ qh, const unsigned short* __restrict__ ql,
    const unsigned short* __restrict__ kh, const unsigned short* __restrict__ kl,
    const unsigned short* __restrict__ vt, float* __restrict__ out) {
  __shared__ __align__(16) unsigned short pbuf[4][16][88];
  const int tid = threadIdx.x;
  const int w = tid >> 6;
  const int lane = tid & 63;
  const int l16 = lane & 15;
  const int g = lane >> 4;
  const int bx = blockIdx.x;
  const int b = blockIdx.y;
  const int tile16 = (w & 1) ? (((w & 2) ? 255 : 127) - bx)
                             : (((w & 2) ? 128 : 0) + bx);
  const int q0 = tile16 * 16;
  const size_t rowbase = (size_t)b * 4096;

  bf16x8 qhf[2], qlf[2];
#pragma unroll
  for (int s = 0; s < 2; ++s) {
    size_t a = (rowbase + q0 + l16) * 64 + s * 32 + g * 8;
    qhf[s] = *reinterpret_cast<const bf16x8*>(&qh[a]);
    qlf[s] = *reinterpret_cast<const bf16x8*>(&ql[a]);
  }
  f32x4 o[4];
  float m_r[4], l_r[4];
#pragma unroll
  for (int hb = 0; hb < 4; ++hb) {
    f32x4 z = {0.f, 0.f, 0.f, 0.f};
    o[hb] = z;
  }
#pragma unroll
  for (int j = 0; j < 4; ++j) { m_r[j] = -1e30f; l_r[j] = 0.f; }

  const int nkv = (q0 + 15) / 64 + 1;
  for (int t = 0; t < nkv; ++t) {
    const int kv0 = t * 64;
    f32x4 s_acc[4];
#pragma unroll
    for (int kb = 0; kb < 4; ++kb) {
      bf16x8 khf[2], klf[2];
#pragma unroll
      for (int s = 0; s < 2; ++s) {
        size_t a = (rowbase + kv0 + kb * 16 + l16) * 64 + s * 32 + g * 8;
        khf[s] = *reinterpret_cast<const bf16x8*>(&kh[a]);
        klf[s] = *reinterpret_cast<const bf16x8*>(&kl[a]);
      }
      f32x4 acc = {0.f, 0.f, 0.f, 0.f};
#pragma unroll
      for (int s = 0; s < 2; ++s) {
        acc = __builtin_amdgcn_mfma_f32_16x16x32_bf16(qhf[s], khf[s], acc, 0, 0, 0);
        acc = __builtin_amdgcn_mfma_f32_16x16x32_bf16(qhf[s], klf[s], acc, 0, 0, 0);
        acc = __builtin_amdgcn_mfma_f32_16x16x32_bf16(qlf[s], khf[s], acc, 0, 0, 0);
      }
      s_acc[kb] = acc;
    }
    if (t == nkv - 1) {
#pragma unroll
      for (int kb = 0; kb < 4; ++kb)
#pragma unroll
        for (int j = 0; j < 4; ++j) {
          int kvg = kv0 + kb * 16 + l16;
          int qg = q0 + 4 * g + j;
          if (kvg > qg) s_acc[kb][j] = -1e30f;
        }
    }
#pragma unroll
    for (int j = 0; j < 4; ++j) {
      float rm = fmaxf(fmaxf(s_acc[0][j], s_acc[1][j]),
                       fmaxf(s_acc[2][j], s_acc[3][j]));
      rm = fmaxf(rm, __shfl_xor(rm, 1));
      rm = fmaxf(rm, __shfl_xor(rm, 2));
      rm = fmaxf(rm, __shfl_xor(rm, 4));
      rm = fmaxf(rm, __shfl_xor(rm, 8));
      float mn = fmaxf(m_r[j], rm);
      float al = __expf(m_r[j] - mn);
      float ps = 0.f;
#pragma unroll
      for (int kb = 0; kb < 4; ++kb) {
        float pv = __expf(s_acc[kb][j] - mn);
        s_acc[kb][j] = pv;
        ps += pv;
      }
      ps += __shfl_xor(ps, 1);
      ps += __shfl_xor(ps, 2);
      ps += __shfl_xor(ps, 4);
      ps += __shfl_xor(ps, 8);
      l_r[j] = l_r[j] * al + ps;
      m_r[j] = mn;
#pragma unroll
      for (int hb = 0; hb < 4; ++hb) o[hb][j] *= al;
    }
#pragma unroll
    for (int kb = 0; kb < 4; ++kb)
#pragma unroll
      for (int j = 0; j < 4; ++j)
        pbuf[w][4 * g + j][kb * 16 + l16] = f2bf(s_acc[kb][j]);
    asm volatile("s_waitcnt lgkmcnt(0)" ::: "memory");
#pragma unroll
    for (int ks = 0; ks < 2; ++ks) {
      bf16x8 pa = *reinterpret_cast<const bf16x8*>(&pbuf[w][l16][ks * 32 + g * 8]);
#pragma unroll
      for (int hb = 0; hb < 4; ++hb) {
        size_t a = ((size_t)b * 64 + hb * 16 + l16) * 4096 + kv0 + ks * 32 + g * 8;
        bf16x8 vfr = *reinterpret_cast<const bf16x8*>(&vt[a]);
        o[hb] = __builtin_amdgcn_mfma_f32_16x16x32_bf16(pa, vfr, o[hb], 0, 0, 0);
      }
    }
  }
#pragma unroll
  for (int hb = 0; hb < 4; ++hb)
#pragma unroll
    for (int j = 0; j < 4; ++j) {
      size_t a = (rowbase + q0 + 4 * g + j) * 64 + hb * 16 + l16;
      out[a] = o[hb][j] / l_r[j];
    }
}

extern "C" void kernel_launch(void* const* d_in, const int* in_sizes, int n_in,
                              void* d_out, int out_size, void* d_ws, size_t ws_size,
                              hipStream_t stream) {
  const float* x  = (const float*)d_in[0];
  const float* Wq = (const float*)d_in[1];
  const float* Wk = (const float*)d_in[2];
  const float* Wv = (const float*)d_in[3];
  float* out = (float*)d_out;

  const size_t N = (size_t)4 * 4096 * 64;   // elements per q/k/v array
  const size_t WN = (size_t)192 * 1024;     // W frag-stream elements
  unsigned short* qh = (unsigned short*)d_ws;
  unsigned short* ql = qh + N;
  unsigned short* kh = ql + N;
  unsigned short* kl = kh + N;
  unsigned short* vt = kl + N;              // [B][64][T] transposed V
  unsigned short* Wth = vt + N;
  unsigned short* Wtl = Wth + WN;
  __half* OP = (__half*)(Wtl + WN);         // 4608 slots x 16 x 64 f16
  float* ML = (float*)(OP + (size_t)4608 * 1024);  // 4608 slots x 32 f32

  const size_t need = (5 * N + 2 * WN) * 2 + (size_t)4608 * 1024 * 2
                      + (size_t)4608 * 32 * 4;

  wsplit_kernel<<<dim3(96), dim3(256), 0, stream>>>(Wq, Wk, Wv, Wth, Wtl);
  proj_mfma_kernel<<<dim3(512), dim3(256), 0, stream>>>(x, Wth, Wtl, qh, ql, kh, kl, vt);
  if (ws_size >= need) {
    attn_part_kernel<<<dim3(256, 8, 4), dim3(64), 0, stream>>>(qh, ql, kh, kl, vt, OP, ML);
    attn_combine_kernel<<<dim3(256, 4), dim3(64), 0, stream>>>(OP, ML, out);
  } else {
    attn_kernel<<<dim3(64, 4), dim3(256), 0, stream>>>(qh, ql, kh, kl, vt, out);
  }
}